// Round 3
// baseline (92.268 us; speedup 1.0000x reference)
//
#include <hip/hip_runtime.h>
#include <math.h>

// NCE loss: scalar output.
//   s_j = (q_j . r_j + bias[t_j]) / E
//   loss = sum_j log_sigmoid(s_j - log(NC*freq[t_j]))
//   noise_loss = sum_j sum_k log_sigmoid(-(s_j - log(NC*freq[noises[j + k*B]])))
//   out = -(loss + noise_loss)/B + 10*(sum q^2 + sum r^2)/(E*B)
//
// Layout: 256-thread block = 16 pairs x 16 e-chunks (8 elems each).
// 1024 blocks -> 4 blocks/CU, 16 waves/CU (2x R2's TLP).
// Noise freq lookups are prefetched in Phase A so their dependent-gather
// latency hides under the embed column gather.

#define PAIRS 16
#define GSPLIT 16

__device__ __forceinline__ float log_sigmoid_f(float x) {
    // jax.nn.log_sigmoid(x) = min(x,0) - log1p(exp(-|x|))
    return fminf(x, 0.0f) - log1pf(expf(-fabsf(x)));
}

__global__ __launch_bounds__(256) void nce_kernel(
    const float* __restrict__ embed,
    const float* __restrict__ bias,
    const float* __restrict__ freq,
    const int*   __restrict__ targets,
    const int*   __restrict__ contexts,
    const int*   __restrict__ noises,
    float*       __restrict__ block_partials,
    int V, int E, int B, int NC)
{
    __shared__ float sh_dot[PAIRS][GSPLIT + 1];
    __shared__ float sh_sq [PAIRS][GSPLIT + 1];
    __shared__ float sh_s  [PAIRS];
    __shared__ float sh_wred[4];

    const int p = threadIdx.x & (PAIRS - 1);
    const int g = threadIdx.x >> 4;          // 0..15
    const int j = blockIdx.x * PAIRS + p;
    const bool valid = (j < B);

    float contrib = 0.0f;

    // ---- Phase A: embed gather + noise/bias prefetch ----
    float dot = 0.0f, sq = 0.0f;
    float lg0 = 0.0f;                        // log(NC*freq[noise_g]) prefetch
    bool  has0 = false;
    float bval = 0.0f, lgt = 0.0f;           // per-pair (g==0 thread only)
    if (valid) {
        const int t = targets[j];
        const int c = contexts[j];
        if (g < NC) {
            const int n = noises[j + (size_t)g * B];
            lg0 = logf((float)NC * freq[n]);
            has0 = true;
        }
        if (g == 0) {
            bval = bias[t];
            lgt  = logf((float)NC * freq[t]);
        }
        const int epc = E / GSPLIT;          // 8 for E=128
        const int e0  = g * epc;
        const float* ct = embed + t;
        const float* cc = embed + c;
        #pragma unroll 8
        for (int e = e0; e < e0 + epc; ++e) {
            float qe = ct[(size_t)e * V];
            float re = cc[(size_t)e * V];
            dot = fmaf(qe, re, dot);
            sq  = fmaf(qe, qe, fmaf(re, re, sq));
        }
    }
    sh_dot[p][g] = dot;
    sh_sq [p][g] = sq;
    __syncthreads();

    // ---- Phase B: per-pair s, positive term, penalty ----
    // threads 0..PAIRS-1 are exactly (p==tid, g==0) -> have bval/lgt in regs
    if (threadIdx.x < PAIRS) {
        float d = 0.0f, s2 = 0.0f;
        #pragma unroll
        for (int gg = 0; gg < GSPLIT; ++gg) {
            d  += sh_dot[threadIdx.x][gg];
            s2 += sh_sq [threadIdx.x][gg];
        }
        float sval = 0.0f;
        if (valid) {
            sval = (d + bval) / (float)E;
            const float pos = log_sigmoid_f(sval - lgt);
            contrib += -pos / (float)B + 10.0f * s2 / ((float)E * (float)B);
        }
        sh_s[threadIdx.x] = sval;
    }
    __syncthreads();

    // ---- Phase C: noise terms (freq logs already in registers) ----
    if (valid) {
        const float sval = sh_s[p];
        float nacc = 0.0f;
        if (has0) nacc = log_sigmoid_f(-(sval - lg0));
        for (int k = g + GSPLIT; k < NC; k += GSPLIT) {   // not taken for NC<=16
            const int n = noises[j + (size_t)k * B];
            nacc += log_sigmoid_f(-(sval - logf((float)NC * freq[n])));
        }
        contrib += -nacc / (float)B;
    }

    // ---- Phase D: block reduction ----
    #pragma unroll
    for (int off = 32; off > 0; off >>= 1)
        contrib += __shfl_xor(contrib, off, 64);
    const int wave = threadIdx.x >> 6;
    const int lane = threadIdx.x & 63;
    if (lane == 0) sh_wred[wave] = contrib;
    __syncthreads();
    if (threadIdx.x == 0)
        block_partials[blockIdx.x] =
            sh_wred[0] + sh_wred[1] + sh_wred[2] + sh_wred[3];
}

__global__ __launch_bounds__(256) void reduce_partials_kernel(
    const float* __restrict__ parts, int n, float* __restrict__ out)
{
    __shared__ double sh[256];
    double a = 0.0;
    for (int i = threadIdx.x; i < n; i += 256) a += (double)parts[i];
    sh[threadIdx.x] = a;
    __syncthreads();
    for (int s = 128; s > 0; s >>= 1) {
        if (threadIdx.x < s) sh[threadIdx.x] += sh[threadIdx.x + s];
        __syncthreads();
    }
    if (threadIdx.x == 0) out[0] = (float)sh[0];
}

extern "C" void kernel_launch(void* const* d_in, const int* in_sizes, int n_in,
                              void* d_out, int out_size, void* d_ws, size_t ws_size,
                              hipStream_t stream) {
    const float* embed    = (const float*)d_in[0];
    const float* bias     = (const float*)d_in[1];
    const float* freq     = (const float*)d_in[2];
    const int*   targets  = (const int*)d_in[3];
    const int*   contexts = (const int*)d_in[4];
    const int*   noises   = (const int*)d_in[5];

    const int V  = in_sizes[2];              // vocab (1e6)
    const int E  = in_sizes[0] / V;          // embed dim (128)
    const int B  = in_sizes[3];              // batch (16384)
    const int NC = in_sizes[5] / B;          // noise count (16)

    float* partials = (float*)d_ws;

    const int nblocks = (B + PAIRS - 1) / PAIRS;   // 1024 for B=16384

    nce_kernel<<<nblocks, 256, 0, stream>>>(
        embed, bias, freq, targets, contexts, noises, partials, V, E, B, NC);

    reduce_partials_kernel<<<1, 256, 0, stream>>>(
        partials, nblocks, (float*)d_out);
}